// Round 1
// baseline (963.330 us; speedup 1.0000x reference)
//
#include <hip/hip_runtime.h>

typedef float f32x4 __attribute__((ext_vector_type(4)));
typedef short bf16x8 __attribute__((ext_vector_type(8)));
typedef unsigned short u16;

#define B_SZ 4
#define S_SZ 4096
#define H_SZ 1024
#define F_SZ 4096
#define CHUNK_SZ 512
#define NCHUNK 8
#define MCH (B_SZ * CHUNK_SZ)   // 2048 rows per chunk
#define LRATE 0.001f

__device__ __forceinline__ u16 f2bf(float f) {
  unsigned u = __float_as_uint(f);
  u += 0x7FFFu + ((u >> 16) & 1u);   // round-to-nearest-even
  return (u16)(u >> 16);
}

__device__ __forceinline__ void gload_lds16(const void* g, void* l) {
  __builtin_amdgcn_global_load_lds(
      (const __attribute__((address_space(1))) unsigned int*)g,
      (__attribute__((address_space(3))) unsigned int*)l, 16, 0, 0);
}

// ---------------- converts ----------------

__global__ __launch_bounds__(256) void k_init(float* scal) {
  if (threadIdx.x == 0) { scal[0] = 1.f; scal[1] = 0.f; }
}

__global__ __launch_bounds__(256) void k_cvt_x(const float* __restrict__ x,
                                               u16* __restrict__ xb) {
  size_t i = ((size_t)blockIdx.x * 256 + threadIdx.x) * 8;
  float4 v0 = *(const float4*)(x + i);
  float4 v1 = *(const float4*)(x + i + 4);
  union { u16 u[8]; bf16x8 v; } o;
  o.u[0] = f2bf(v0.x); o.u[1] = f2bf(v0.y); o.u[2] = f2bf(v0.z); o.u[3] = f2bf(v0.w);
  o.u[4] = f2bf(v1.x); o.u[5] = f2bf(v1.y); o.u[6] = f2bf(v1.z); o.u[7] = f2bf(v1.w);
  *(bf16x8*)(xb + i) = o.v;
}

// W [R][C] fp32  ->  Wt [C][R] bf16
__global__ __launch_bounds__(256) void k_transpose_cvt(const float* __restrict__ W,
                                                       u16* __restrict__ Wt,
                                                       int R, int C) {
  __shared__ float tile[32][33];
  int tx = threadIdx.x & 31, ty = threadIdx.x >> 5;
  int r0 = blockIdx.y << 5, c0 = blockIdx.x << 5;
#pragma unroll
  for (int i = 0; i < 4; i++)
    tile[ty + i * 8][tx] = W[(size_t)(r0 + ty + i * 8) * C + c0 + tx];
  __syncthreads();
#pragma unroll
  for (int i = 0; i < 4; i++)
    Wt[(size_t)(c0 + ty + i * 8) * R + r0 + tx] = f2bf(tile[tx][ty + i * 8]);
}

// ---------------- GEMM 1: G = Xc@W0, U = Xc@W2, fused SwiGLU -> h (bf16) ----------------
// tile 128(M) x 64(N), BK=32, 4 waves (2x2), per-wave 64x32 = 4x2 frags of 16x16
__global__ __launch_bounds__(256) void k_gemm_gu(
    const u16* __restrict__ xb,   // [B][S][H] bf16
    const u16* __restrict__ w0t,  // [F][H] bf16 (w0^T)
    const u16* __restrict__ w2t,  // [F][H]
    u16* __restrict__ hbuf,       // [2048][F] bf16
    const float* __restrict__ scal, int chunk) {
  __shared__ __align__(16) u16 sA[128 * 32];
  __shared__ __align__(16) u16 sB0[64 * 32];
  __shared__ __align__(16) u16 sB2[64 * 32];

  int t = threadIdx.x;
  int lane = t & 63, wid = t >> 6;
  int wm = wid >> 1, wn = wid & 1;
  int tm = blockIdx.x, tn = blockIdx.y;

  int gm0 = tm << 7;               // chunk-local row 0 of tile
  int bb = gm0 >> 9;               // batch (tile never crosses batch: 128 | 512)
  int pos0 = gm0 & 511;
  const u16* Abase = xb + ((size_t)bb * S_SZ + (size_t)chunk * CHUNK_SZ + pos0) * H_SZ;
  const u16* B0base = w0t + (size_t)(tn << 6) * H_SZ;
  const u16* B2base = w2t + (size_t)(tn << 6) * H_SZ;

  const u16* aSrc0 = Abase + (t >> 2) * H_SZ + ((t & 3) << 3);
  const u16* aSrc1 = aSrc0 + 64 * H_SZ;
  const u16* bSrc0 = B0base + (t >> 2) * H_SZ + ((t & 3) << 3);
  const u16* bSrc2 = B2base + (t >> 2) * H_SZ + ((t & 3) << 3);

  char* aDst0 = (char*)sA + t * 16;
  char* aDst1 = (char*)sA + 4096 + t * 16;
  char* bDst0 = (char*)sB0 + t * 16;
  char* bDst2 = (char*)sB2 + t * 16;

  f32x4 acc0[4][2], acc2[4][2];
#pragma unroll
  for (int i = 0; i < 4; i++)
#pragma unroll
    for (int j = 0; j < 2; j++)
#pragma unroll
      for (int k = 0; k < 4; k++) { acc0[i][j][k] = 0.f; acc2[i][j][k] = 0.f; }

  const int aoff = ((wm << 6) + (lane & 15)) * 64 + ((lane >> 4) << 4);
  const int boff = ((wn << 5) + (lane & 15)) * 64 + ((lane >> 4) << 4);

  for (int k0 = 0; k0 < H_SZ; k0 += 32) {
    gload_lds16(aSrc0, aDst0);
    gload_lds16(aSrc1, aDst1);
    gload_lds16(bSrc0, bDst0);
    gload_lds16(bSrc2, bDst2);
    aSrc0 += 32; aSrc1 += 32; bSrc0 += 32; bSrc2 += 32;
    __syncthreads();

    bf16x8 av[4], b0v[2], b2v[2];
#pragma unroll
    for (int fr = 0; fr < 4; fr++)
      av[fr] = *(const bf16x8*)((const char*)sA + aoff + fr * 1024);
#pragma unroll
    for (int fc = 0; fc < 2; fc++) {
      b0v[fc] = *(const bf16x8*)((const char*)sB0 + boff + fc * 1024);
      b2v[fc] = *(const bf16x8*)((const char*)sB2 + boff + fc * 1024);
    }
#pragma unroll
    for (int fr = 0; fr < 4; fr++)
#pragma unroll
      for (int fc = 0; fc < 2; fc++) {
        acc0[fr][fc] = __builtin_amdgcn_mfma_f32_16x16x32_bf16(av[fr], b0v[fc], acc0[fr][fc], 0, 0, 0);
        acc2[fr][fc] = __builtin_amdgcn_mfma_f32_16x16x32_bf16(av[fr], b2v[fc], acc2[fr][fc], 0, 0, 0);
      }
    __syncthreads();
  }

  float D = scal[0];
#pragma unroll
  for (int fr = 0; fr < 4; fr++)
#pragma unroll
    for (int fc = 0; fc < 2; fc++) {
      int row0 = (tm << 7) + (wm << 6) + (fr << 4) + ((lane >> 4) << 2);
      int col = (tn << 6) + (wn << 5) + (fc << 4) + (lane & 15);
#pragma unroll
      for (int j = 0; j < 4; j++) {
        float g = D * acc0[fr][fc][j];
        float u = D * acc2[fr][fc][j];
        float sil = g / (1.f + __expf(-g));
        hbuf[(size_t)(row0 + j) * F_SZ + col] = f2bf(sil * u);
      }
    }
}

// ---------------- GEMM 2: out = D*(h@W1), + squared-error partial sums ----------------
__global__ __launch_bounds__(256) void k_gemm_out(
    const u16* __restrict__ hbuf,  // [2048][F]
    const u16* __restrict__ w1t,   // [H][F] (w1^T)
    const float* __restrict__ x,   // fp32 original
    float* __restrict__ out,
    const float* __restrict__ scal,
    float* __restrict__ partials, int chunk) {
  __shared__ __align__(16) u16 sA[128 * 32];
  __shared__ __align__(16) u16 sB[64 * 32];
  __shared__ float red[256];

  int t = threadIdx.x;
  int lane = t & 63, wid = t >> 6;
  int wm = wid >> 1, wn = wid & 1;
  int tm = blockIdx.x, tn = blockIdx.y;

  const u16* aSrc0 = hbuf + (size_t)(tm << 7) * F_SZ + (t >> 2) * F_SZ + ((t & 3) << 3);
  const u16* aSrc1 = aSrc0 + (size_t)64 * F_SZ;
  const u16* bSrc = w1t + (size_t)(tn << 6) * F_SZ + (t >> 2) * F_SZ + ((t & 3) << 3);

  char* aDst0 = (char*)sA + t * 16;
  char* aDst1 = (char*)sA + 4096 + t * 16;
  char* bDst = (char*)sB + t * 16;

  f32x4 acc[4][2];
#pragma unroll
  for (int i = 0; i < 4; i++)
#pragma unroll
    for (int j = 0; j < 2; j++)
#pragma unroll
      for (int k = 0; k < 4; k++) acc[i][j][k] = 0.f;

  const int aoff = ((wm << 6) + (lane & 15)) * 64 + ((lane >> 4) << 4);
  const int boff = ((wn << 5) + (lane & 15)) * 64 + ((lane >> 4) << 4);

  for (int k0 = 0; k0 < F_SZ; k0 += 32) {
    gload_lds16(aSrc0, aDst0);
    gload_lds16(aSrc1, aDst1);
    gload_lds16(bSrc, bDst);
    aSrc0 += 32; aSrc1 += 32; bSrc += 32;
    __syncthreads();

    bf16x8 av[4], bv[2];
#pragma unroll
    for (int fr = 0; fr < 4; fr++)
      av[fr] = *(const bf16x8*)((const char*)sA + aoff + fr * 1024);
#pragma unroll
    for (int fc = 0; fc < 2; fc++)
      bv[fc] = *(const bf16x8*)((const char*)sB + boff + fc * 1024);
#pragma unroll
    for (int fr = 0; fr < 4; fr++)
#pragma unroll
      for (int fc = 0; fc < 2; fc++)
        acc[fr][fc] = __builtin_amdgcn_mfma_f32_16x16x32_bf16(av[fr], bv[fc], acc[fr][fc], 0, 0, 0);
    __syncthreads();
  }

  float D = scal[0];
  float psum = 0.f;
#pragma unroll
  for (int fr = 0; fr < 4; fr++)
#pragma unroll
    for (int fc = 0; fc < 2; fc++) {
      int row0 = (tm << 7) + (wm << 6) + (fr << 4) + ((lane >> 4) << 2);
      int col = (tn << 6) + (wn << 5) + (fc << 4) + (lane & 15);
#pragma unroll
      for (int j = 0; j < 4; j++) {
        int row = row0 + j;                 // chunk-local 0..2047
        int bb = row >> 9, pos = row & 511;
        size_t off = ((size_t)bb * S_SZ + (size_t)chunk * CHUNK_SZ + pos) * H_SZ + col;
        float o = D * acc[fr][fc][j];
        out[off] = o;
        float e = o - x[off];
        psum += e * e;
      }
    }

  red[t] = psum;
  __syncthreads();
  for (int s = 128; s > 0; s >>= 1) {
    if (t < s) red[t] += red[t + s];
    __syncthreads();
  }
  if (t == 0) partials[blockIdx.y * gridDim.x + blockIdx.x] = red[0];
}

// ---------------- scalar chain update ----------------
__global__ __launch_bounds__(64) void k_update(float* scal, const float* __restrict__ partials,
                                               float* lossout, int chunk) {
  if (threadIdx.x == 0) {
    float s = 0.f;
    for (int i = 0; i < 256; i++) s += partials[i];
    float loss = s / (float)((size_t)MCH * H_SZ);
    float total = scal[1] + loss;
    scal[1] = total;
    scal[0] = scal[0] * (1.f - LRATE * loss);
    if (chunk == NCHUNK - 1) lossout[0] = total / (float)NCHUNK;
  }
}

// ---------------- launch ----------------
extern "C" void kernel_launch(void* const* d_in, const int* in_sizes, int n_in,
                              void* d_out, int out_size, void* d_ws, size_t ws_size,
                              hipStream_t stream) {
  const float* x = (const float*)d_in[0];
  const float* w0 = (const float*)d_in[1];
  const float* w1 = (const float*)d_in[2];
  const float* w2 = (const float*)d_in[3];
  float* out = (float*)d_out;

  char* ws = (char*)d_ws;
  float* scal = (float*)ws;                    // [0]=D, [1]=total_loss
  float* partials = (float*)(ws + 1024);       // 256 floats
  u16* xb = (u16*)(ws + 8192);                           // 16M elems
  u16* w0t = xb + (size_t)B_SZ * S_SZ * H_SZ;            // 4M
  u16* w2t = w0t + (size_t)H_SZ * F_SZ;                  // 4M
  u16* w1t = w2t + (size_t)H_SZ * F_SZ;                  // 4M
  u16* hbuf = w1t + (size_t)F_SZ * H_SZ;                 // 8M elems (2048 x 4096)

  k_init<<<1, 64, 0, stream>>>(scal);
  k_cvt_x<<<(B_SZ * S_SZ * H_SZ) / (256 * 8), 256, 0, stream>>>(x, xb);
  k_transpose_cvt<<<dim3(F_SZ / 32, H_SZ / 32), 256, 0, stream>>>(w0, w0t, H_SZ, F_SZ);
  k_transpose_cvt<<<dim3(H_SZ / 32, F_SZ / 32), 256, 0, stream>>>(w1, w1t, F_SZ, H_SZ);
  k_transpose_cvt<<<dim3(F_SZ / 32, H_SZ / 32), 256, 0, stream>>>(w2, w2t, H_SZ, F_SZ);

  float* lossout = out + (size_t)B_SZ * S_SZ * H_SZ;
  for (int c = 0; c < NCHUNK; c++) {
    k_gemm_gu<<<dim3(16, 64), 256, 0, stream>>>(xb, w0t, w2t, hbuf, scal, c);
    k_gemm_out<<<dim3(16, 16), 256, 0, stream>>>(hbuf, w1t, x, out, scal, partials, c);
    k_update<<<1, 64, 0, stream>>>(scal, partials, lossout, c);
  }
}

// Round 2
// 627.431 us; speedup vs baseline: 1.5354x; 1.5354x over previous
//
#include <hip/hip_runtime.h>

typedef float f32x4 __attribute__((ext_vector_type(4)));
typedef short bf16x8 __attribute__((ext_vector_type(8)));
typedef unsigned short u16;

#define B_SZ 4
#define S_SZ 4096
#define H_SZ 1024
#define F_SZ 4096
#define CHUNK_SZ 512
#define NCHUNK 8
#define MCH 2048            // rows per chunk (B*CHUNK)
#define LRATE 0.001f
#define NSPLIT 4            // split-K factor for GEMM2

__device__ __forceinline__ u16 f2bf(float f) {
  unsigned u = __float_as_uint(f);
  u += 0x7FFFu + ((u >> 16) & 1u);   // round-to-nearest-even
  return (u16)(u >> 16);
}
__device__ __forceinline__ float bf2f(u16 u) {
  return __uint_as_float(((unsigned)u) << 16);
}

__device__ __forceinline__ void gload_lds16(const void* g, void* l) {
  __builtin_amdgcn_global_load_lds(
      (const __attribute__((address_space(1))) unsigned int*)g,
      (__attribute__((address_space(3))) unsigned int*)l, 16, 0, 0);
}

// ---------------- converts ----------------

__global__ __launch_bounds__(256) void k_init(float* scal) {
  if (threadIdx.x == 0) { scal[0] = 1.f; scal[1] = 0.f; }
}

__global__ __launch_bounds__(256) void k_cvt_x(const float* __restrict__ x,
                                               u16* __restrict__ xb) {
  size_t i = ((size_t)blockIdx.x * 256 + threadIdx.x) * 8;
  float4 v0 = *(const float4*)(x + i);
  float4 v1 = *(const float4*)(x + i + 4);
  union { u16 u[8]; bf16x8 v; } o;
  o.u[0] = f2bf(v0.x); o.u[1] = f2bf(v0.y); o.u[2] = f2bf(v0.z); o.u[3] = f2bf(v0.w);
  o.u[4] = f2bf(v1.x); o.u[5] = f2bf(v1.y); o.u[6] = f2bf(v1.z); o.u[7] = f2bf(v1.w);
  *(bf16x8*)(xb + i) = o.v;
}

// W [R][C] fp32  ->  Wt [C][R] bf16
__global__ __launch_bounds__(256) void k_transpose_cvt(const float* __restrict__ W,
                                                       u16* __restrict__ Wt,
                                                       int R, int C) {
  __shared__ float tile[32][33];
  int tx = threadIdx.x & 31, ty = threadIdx.x >> 5;
  int r0 = blockIdx.y << 5, c0 = blockIdx.x << 5;
#pragma unroll
  for (int i = 0; i < 4; i++)
    tile[ty + i * 8][tx] = W[(size_t)(r0 + ty + i * 8) * C + c0 + tx];
  __syncthreads();
#pragma unroll
  for (int i = 0; i < 4; i++)
    Wt[(size_t)(c0 + ty + i * 8) * R + r0 + tx] = f2bf(tile[tx][ty + i * 8]);
}

// ---------------- GEMM 1: G = Xc@W0, U = Xc@W2, fused SwiGLU -> h (bf16) ----------------
// tile 128(M) x 64(N), BK=64, 4 waves (2x2), XOR-swizzled LDS (pre-swizzled source)
__global__ __launch_bounds__(256) void k_gemm_gu(
    const u16* __restrict__ xb,   // [B][S][H] bf16
    const u16* __restrict__ w0t,  // [F][H] bf16 (w0^T)
    const u16* __restrict__ w2t,  // [F][H]
    u16* __restrict__ hbuf,       // [2048][F] bf16
    const float* __restrict__ scal, int chunk) {
  __shared__ __align__(16) u16 sA[128 * 64];   // 16KB
  __shared__ __align__(16) u16 sB0[64 * 64];   // 8KB
  __shared__ __align__(16) u16 sB2[64 * 64];   // 8KB

  int t = threadIdx.x;
  int lane = t & 63, wid = t >> 6;
  int wm = wid >> 1, wn = wid & 1;
  int tm = blockIdx.x, tn = blockIdx.y;

  int gm0 = tm << 7;               // chunk-local row 0 of tile
  int bb = gm0 >> 9;               // batch (tile never crosses batch)
  int pos0 = gm0 & 511;
  const u16* Abase = xb + ((size_t)bb * S_SZ + (size_t)chunk * CHUNK_SZ + pos0) * H_SZ;

  // staging: thread t writes LDS row (t>>3)+32r, slot (t&7); source column is
  // slot XOR (row&7) so that LDS[row][slot] holds global col (slot^(row&7)).
  int srow = t >> 3;
  int scol = (((t & 7) ^ (srow & 7)) << 3);   // in elements
  const u16* aSrc  = Abase + (size_t)srow * H_SZ + scol;
  const u16* b0Src = w0t + ((size_t)(tn << 6) + srow) * H_SZ + scol;
  const u16* b2Src = w2t + ((size_t)(tn << 6) + srow) * H_SZ + scol;
  char* aDst  = (char*)sA  + t * 16;
  char* b0Dst = (char*)sB0 + t * 16;
  char* b2Dst = (char*)sB2 + t * 16;

  f32x4 acc0[4][2], acc2[4][2];
#pragma unroll
  for (int i = 0; i < 4; i++)
#pragma unroll
    for (int j = 0; j < 2; j++)
#pragma unroll
      for (int k = 0; k < 4; k++) { acc0[i][j][k] = 0.f; acc2[i][j][k] = 0.f; }

  // fragment read addresses (swizzled): row&7 == lane&7 for all fr/fc
  int arow = (wm << 6) + (lane & 15);
  int brow = (wn << 5) + (lane & 15);
  int sl0 = (lane >> 4) ^ (lane & 7);
  int sl1 = ((lane >> 4) | 4) ^ (lane & 7);
  const char* aP0 = (const char*)sA + arow * 128 + sl0 * 16;
  const char* aP1 = (const char*)sA + arow * 128 + sl1 * 16;
  const char* b0P0 = (const char*)sB0 + brow * 128 + sl0 * 16;
  const char* b0P1 = (const char*)sB0 + brow * 128 + sl1 * 16;
  const char* b2P0 = (const char*)sB2 + brow * 128 + sl0 * 16;
  const char* b2P1 = (const char*)sB2 + brow * 128 + sl1 * 16;

  for (int k0 = 0; k0 < H_SZ; k0 += 64) {
#pragma unroll
    for (int r = 0; r < 4; r++)
      gload_lds16(aSrc + (size_t)r * 32 * H_SZ, aDst + r * 4096);
#pragma unroll
    for (int r = 0; r < 2; r++) {
      gload_lds16(b0Src + (size_t)r * 32 * H_SZ, b0Dst + r * 4096);
      gload_lds16(b2Src + (size_t)r * 32 * H_SZ, b2Dst + r * 4096);
    }
    aSrc += 64; b0Src += 64; b2Src += 64;
    __syncthreads();

    {
      bf16x8 av[4], b0v[2], b2v[2];
#pragma unroll
      for (int fr = 0; fr < 4; fr++) av[fr] = *(const bf16x8*)(aP0 + fr * 2048);
#pragma unroll
      for (int fc = 0; fc < 2; fc++) {
        b0v[fc] = *(const bf16x8*)(b0P0 + fc * 2048);
        b2v[fc] = *(const bf16x8*)(b2P0 + fc * 2048);
      }
#pragma unroll
      for (int fr = 0; fr < 4; fr++)
#pragma unroll
        for (int fc = 0; fc < 2; fc++) {
          acc0[fr][fc] = __builtin_amdgcn_mfma_f32_16x16x32_bf16(av[fr], b0v[fc], acc0[fr][fc], 0, 0, 0);
          acc2[fr][fc] = __builtin_amdgcn_mfma_f32_16x16x32_bf16(av[fr], b2v[fc], acc2[fr][fc], 0, 0, 0);
        }
    }
    {
      bf16x8 av[4], b0v[2], b2v[2];
#pragma unroll
      for (int fr = 0; fr < 4; fr++) av[fr] = *(const bf16x8*)(aP1 + fr * 2048);
#pragma unroll
      for (int fc = 0; fc < 2; fc++) {
        b0v[fc] = *(const bf16x8*)(b0P1 + fc * 2048);
        b2v[fc] = *(const bf16x8*)(b2P1 + fc * 2048);
      }
#pragma unroll
      for (int fr = 0; fr < 4; fr++)
#pragma unroll
        for (int fc = 0; fc < 2; fc++) {
          acc0[fr][fc] = __builtin_amdgcn_mfma_f32_16x16x32_bf16(av[fr], b0v[fc], acc0[fr][fc], 0, 0, 0);
          acc2[fr][fc] = __builtin_amdgcn_mfma_f32_16x16x32_bf16(av[fr], b2v[fc], acc2[fr][fc], 0, 0, 0);
        }
    }
    __syncthreads();
  }

  float D = scal[0];
#pragma unroll
  for (int fr = 0; fr < 4; fr++)
#pragma unroll
    for (int fc = 0; fc < 2; fc++) {
      int row0 = (tm << 7) + (wm << 6) + (fr << 4) + ((lane >> 4) << 2);
      int col = (tn << 6) + (wn << 5) + (fc << 4) + (lane & 15);
#pragma unroll
      for (int j = 0; j < 4; j++) {
        float g = D * acc0[fr][fc][j];
        float u = D * acc2[fr][fc][j];
        float sil = g / (1.f + __expf(-g));
        hbuf[(size_t)(row0 + j) * F_SZ + col] = f2bf(sil * u);
      }
    }
}

// ---------------- GEMM 2 (split-K): pbuf[kz] = h[:,kz*1024:+1024] @ w1t slice ----------------
__global__ __launch_bounds__(256) void k_gemm_out(
    const u16* __restrict__ hbuf,  // [2048][F]
    const u16* __restrict__ w1t,   // [H][F] (w1^T)
    u16* __restrict__ pbuf) {      // [NSPLIT][2048][1024] bf16 partials
  __shared__ __align__(16) u16 sA[128 * 64];
  __shared__ __align__(16) u16 sB[64 * 64];

  int t = threadIdx.x;
  int lane = t & 63, wid = t >> 6;
  int wm = wid >> 1, wn = wid & 1;
  int tm = blockIdx.x, tn = blockIdx.y, kz = blockIdx.z;

  int srow = t >> 3;
  int scol = (((t & 7) ^ (srow & 7)) << 3);
  const u16* aSrc = hbuf + ((size_t)(tm << 7) + srow) * F_SZ + kz * 1024 + scol;
  const u16* bSrc = w1t + ((size_t)(tn << 6) + srow) * F_SZ + kz * 1024 + scol;
  char* aDst = (char*)sA + t * 16;
  char* bDst = (char*)sB + t * 16;

  f32x4 acc[4][2];
#pragma unroll
  for (int i = 0; i < 4; i++)
#pragma unroll
    for (int j = 0; j < 2; j++)
#pragma unroll
      for (int k = 0; k < 4; k++) acc[i][j][k] = 0.f;

  int arow = (wm << 6) + (lane & 15);
  int brow = (wn << 5) + (lane & 15);
  int sl0 = (lane >> 4) ^ (lane & 7);
  int sl1 = ((lane >> 4) | 4) ^ (lane & 7);
  const char* aP0 = (const char*)sA + arow * 128 + sl0 * 16;
  const char* aP1 = (const char*)sA + arow * 128 + sl1 * 16;
  const char* bP0 = (const char*)sB + brow * 128 + sl0 * 16;
  const char* bP1 = (const char*)sB + brow * 128 + sl1 * 16;

  for (int k0 = 0; k0 < 1024; k0 += 64) {
#pragma unroll
    for (int r = 0; r < 4; r++)
      gload_lds16(aSrc + (size_t)r * 32 * F_SZ, aDst + r * 4096);
#pragma unroll
    for (int r = 0; r < 2; r++)
      gload_lds16(bSrc + (size_t)r * 32 * F_SZ, bDst + r * 4096);
    aSrc += 64; bSrc += 64;
    __syncthreads();

    {
      bf16x8 av[4], bv[2];
#pragma unroll
      for (int fr = 0; fr < 4; fr++) av[fr] = *(const bf16x8*)(aP0 + fr * 2048);
#pragma unroll
      for (int fc = 0; fc < 2; fc++) bv[fc] = *(const bf16x8*)(bP0 + fc * 2048);
#pragma unroll
      for (int fr = 0; fr < 4; fr++)
#pragma unroll
        for (int fc = 0; fc < 2; fc++)
          acc[fr][fc] = __builtin_amdgcn_mfma_f32_16x16x32_bf16(av[fr], bv[fc], acc[fr][fc], 0, 0, 0);
    }
    {
      bf16x8 av[4], bv[2];
#pragma unroll
      for (int fr = 0; fr < 4; fr++) av[fr] = *(const bf16x8*)(aP1 + fr * 2048);
#pragma unroll
      for (int fc = 0; fc < 2; fc++) bv[fc] = *(const bf16x8*)(bP1 + fc * 2048);
#pragma unroll
      for (int fr = 0; fr < 4; fr++)
#pragma unroll
        for (int fc = 0; fc < 2; fc++)
          acc[fr][fc] = __builtin_amdgcn_mfma_f32_16x16x32_bf16(av[fr], bv[fc], acc[fr][fc], 0, 0, 0);
    }
    __syncthreads();
  }

#pragma unroll
  for (int fr = 0; fr < 4; fr++)
#pragma unroll
    for (int fc = 0; fc < 2; fc++) {
      int row0 = (tm << 7) + (wm << 6) + (fr << 4) + ((lane >> 4) << 2);
      int col = (tn << 6) + (wn << 5) + (fc << 4) + (lane & 15);
#pragma unroll
      for (int j = 0; j < 4; j++)
        pbuf[((size_t)kz * MCH + row0 + j) * 1024 + col] = f2bf(acc[fr][fc][j]);
    }
}

// ---------------- epilogue: sum split-K partials, scale by D, write out, error reduce ----------------
__global__ __launch_bounds__(256) void k_epilogue(
    const u16* __restrict__ pbuf, const float* __restrict__ x,
    float* __restrict__ out, const float* __restrict__ scal,
    float* __restrict__ partials, int chunk) {
  __shared__ float red[256];
  int t = threadIdx.x;
  size_t base = ((size_t)blockIdx.x * 256 + t) * 8;   // elem index in [2048][1024]
  int row = (int)(base >> 10);
  int col = (int)(base & 1023);
  float D = scal[0];

  float s[8] = {0.f, 0.f, 0.f, 0.f, 0.f, 0.f, 0.f, 0.f};
#pragma unroll
  for (int kz = 0; kz < NSPLIT; kz++) {
    union { bf16x8 v; u16 u[8]; } p;
    p.v = *(const bf16x8*)(pbuf + (size_t)kz * MCH * 1024 + base);
#pragma unroll
    for (int j = 0; j < 8; j++) s[j] += bf2f(p.u[j]);
  }

  int bb = row >> 9, pos = row & 511;
  size_t off = ((size_t)bb * S_SZ + (size_t)chunk * CHUNK_SZ + pos) * H_SZ + col;
  float4 x0 = *(const float4*)(x + off);
  float4 x1 = *(const float4*)(x + off + 4);
  float xv[8] = {x0.x, x0.y, x0.z, x0.w, x1.x, x1.y, x1.z, x1.w};
  float ov[8];
  float psum = 0.f;
#pragma unroll
  for (int j = 0; j < 8; j++) {
    ov[j] = D * s[j];
    float e = ov[j] - xv[j];
    psum += e * e;
  }
  *(float4*)(out + off) = make_float4(ov[0], ov[1], ov[2], ov[3]);
  *(float4*)(out + off + 4) = make_float4(ov[4], ov[5], ov[6], ov[7]);

  red[t] = psum;
  __syncthreads();
  for (int s2 = 128; s2 > 0; s2 >>= 1) {
    if (t < s2) red[t] += red[t + s2];
    __syncthreads();
  }
  if (t == 0) partials[blockIdx.x] = red[0];
}

// ---------------- scalar chain update ----------------
__global__ __launch_bounds__(256) void k_update(float* scal, const float* __restrict__ partials,
                                                float* lossout, int chunk) {
  __shared__ float red[256];
  int t = threadIdx.x;
  float s = 0.f;
  for (int i = t; i < 1024; i += 256) s += partials[i];
  red[t] = s;
  __syncthreads();
  for (int s2 = 128; s2 > 0; s2 >>= 1) {
    if (t < s2) red[t] += red[t + s2];
    __syncthreads();
  }
  if (t == 0) {
    float loss = red[0] / (float)((size_t)MCH * H_SZ);
    float total = scal[1] + loss;
    scal[1] = total;
    scal[0] = scal[0] * (1.f - LRATE * loss);
    if (chunk == NCHUNK - 1) lossout[0] = total / (float)NCHUNK;
  }
}

// ---------------- launch ----------------
extern "C" void kernel_launch(void* const* d_in, const int* in_sizes, int n_in,
                              void* d_out, int out_size, void* d_ws, size_t ws_size,
                              hipStream_t stream) {
  const float* x = (const float*)d_in[0];
  const float* w0 = (const float*)d_in[1];
  const float* w1 = (const float*)d_in[2];
  const float* w2 = (const float*)d_in[3];
  float* out = (float*)d_out;

  char* ws = (char*)d_ws;
  float* scal = (float*)ws;                    // [0]=D, [1]=total_loss
  float* partials = (float*)(ws + 1024);       // 1024 floats
  u16* xb = (u16*)(ws + 8192);                           // 16M elems (32MB)
  u16* w0t = xb + (size_t)B_SZ * S_SZ * H_SZ;            // 4M (8MB)
  u16* w2t = w0t + (size_t)H_SZ * F_SZ;                  // 4M
  u16* w1t = w2t + (size_t)H_SZ * F_SZ;                  // 4M
  u16* hbuf = w1t + (size_t)F_SZ * H_SZ;                 // 8M elems (16MB)
  u16* pbuf = hbuf + (size_t)MCH * F_SZ;                 // NSPLIT*2M elems (16MB)

  k_init<<<1, 256, 0, stream>>>(scal);
  k_cvt_x<<<(B_SZ * S_SZ * H_SZ) / (256 * 8), 256, 0, stream>>>(x, xb);
  k_transpose_cvt<<<dim3(F_SZ / 32, H_SZ / 32), 256, 0, stream>>>(w0, w0t, H_SZ, F_SZ);
  k_transpose_cvt<<<dim3(H_SZ / 32, F_SZ / 32), 256, 0, stream>>>(w1, w1t, F_SZ, H_SZ);
  k_transpose_cvt<<<dim3(F_SZ / 32, H_SZ / 32), 256, 0, stream>>>(w2, w2t, H_SZ, F_SZ);

  float* lossout = out + (size_t)B_SZ * S_SZ * H_SZ;
  for (int c = 0; c < NCHUNK; c++) {
    k_gemm_gu<<<dim3(16, 64), 256, 0, stream>>>(xb, w0t, w2t, hbuf, scal, c);
    k_gemm_out<<<dim3(16, 16, NSPLIT), 256, 0, stream>>>(hbuf, w1t, pbuf);
    k_epilogue<<<1024, 256, 0, stream>>>(pbuf, x, out, scal, partials, c);
    k_update<<<1, 256, 0, stream>>>(scal, partials, lossout, c);
  }
}